// Round 1
// baseline (1015.233 us; speedup 1.0000x reference)
//
#include <hip/hip_runtime.h>
#include <hip/hip_bf16.h>
#include <stdint.h>

#define N_TOK 8192
#define CDIM  1024
#define HDIM  4096
#define NEXP  8

typedef __attribute__((ext_vector_type(8))) short bf16x8;
typedef __attribute__((ext_vector_type(4))) float f32x4;

static __device__ __forceinline__ uint16_t f2bf(float f) {
  union { float f; uint32_t u; } v; v.f = f;
  uint32_t r = v.u + 0x7FFF + ((v.u >> 16) & 1);
  return (uint16_t)(r >> 16);
}

__device__ __forceinline__ void gload_lds16(const void* g, void* l) {
  __builtin_amdgcn_global_load_lds(
      (const __attribute__((address_space(1))) uint32_t*)g,
      (__attribute__((address_space(3))) uint32_t*)l, 16, 0, 0);
}

// ---------------- x -> bf16 ----------------
__global__ void cvt_x_kernel(const float* __restrict__ x, uint16_t* __restrict__ xb) {
  int i = blockIdx.x * 256 + threadIdx.x;   // one thread = 8 elements
  const float4* p = (const float4*)x + (size_t)i * 2;
  float4 a = p[0], b = p[1];
  bf16x8 o;
  o[0] = (short)f2bf(a.x); o[1] = (short)f2bf(a.y);
  o[2] = (short)f2bf(a.z); o[3] = (short)f2bf(a.w);
  o[4] = (short)f2bf(b.x); o[5] = (short)f2bf(b.y);
  o[6] = (short)f2bf(b.z); o[7] = (short)f2bf(b.w);
  *(bf16x8*)(xb + (size_t)i * 8) = o;
}

// ---------------- transpose + convert: src [R][S] f32 -> dst [S][R] bf16, per expert z ----
__global__ void transcvt_kernel(const float* __restrict__ src, uint16_t* __restrict__ dst,
                                int R, int S) {
  __shared__ float tile[32][33];
  const float* s = src + (size_t)blockIdx.z * R * S;
  uint16_t*    d = dst + (size_t)blockIdx.z * R * S;
  int c0 = blockIdx.x * 32, r0 = blockIdx.y * 32;
  int tx = threadIdx.x, ty = threadIdx.y;  // 32 x 8
#pragma unroll
  for (int k = 0; k < 32; k += 8)
    tile[ty + k][tx] = s[(size_t)(r0 + ty + k) * S + c0 + tx];
  __syncthreads();
#pragma unroll
  for (int k = 0; k < 32; k += 8)
    d[(size_t)(c0 + ty + k) * R + r0 + tx] = f2bf(tile[tx][ty + k]);
}

// ---------------- router: one wave per token ----------------
__global__ void router_kernel(const float* __restrict__ x, const float* __restrict__ Wr,
                              int* __restrict__ cnt, int* __restrict__ te,
                              float* __restrict__ tw) {
  int wid = (blockIdx.x * blockDim.x + threadIdx.x) >> 6;
  int lane = threadIdx.x & 63;
  if (wid >= N_TOK) return;
  const float* xr = x + (size_t)wid * CDIM;
  float p[NEXP];
#pragma unroll
  for (int e = 0; e < NEXP; e++) p[e] = 0.f;
  for (int kk = 0; kk < CDIM / 64; kk++) {
    float xv = xr[kk * 64 + lane];
#pragma unroll
    for (int e = 0; e < NEXP; e++)
      p[e] += xv * Wr[e * CDIM + kk * 64 + lane];
  }
#pragma unroll
  for (int e = 0; e < NEXP; e++) {
    float v = p[e];
#pragma unroll
    for (int s = 32; s > 0; s >>= 1) v += __shfl_xor(v, s);
    p[e] = v;
  }
  if (lane == 0) {
    float m0 = -1e30f, m1 = -1e30f; int i0 = 0, i1 = 0;
#pragma unroll
    for (int e = 0; e < NEXP; e++) {
      float v = p[e];
      if (v > m0) { m1 = m0; i1 = i0; m0 = v; i0 = e; }
      else if (v > m1) { m1 = v; i1 = e; }
    }
    float w0 = 1.f / (1.f + __expf(m1 - m0));
    te[wid] = i0 | (i1 << 16);
    tw[wid] = w0;
    atomicAdd(&cnt[i0], 1);
    atomicAdd(&cnt[i1], 1);
  }
}

__global__ void prefix_kernel(const int* __restrict__ cnt, int* __restrict__ offs,
                              int* __restrict__ fill) {
  if (threadIdx.x == 0) {
    int acc = 0;
    for (int e = 0; e < NEXP; e++) { offs[e] = acc; fill[e] = acc; acc += cnt[e]; }
    offs[NEXP] = acc;
  }
}

__global__ void bucket_kernel(const int* __restrict__ te, const float* __restrict__ tw,
                              int* __restrict__ fill, int* __restrict__ perm,
                              float* __restrict__ pw) {
  int t = blockIdx.x * 256 + threadIdx.x;
  if (t >= N_TOK) return;
  int e01 = te[t];
  int e0 = e01 & 0xffff, e1 = e01 >> 16;
  float w0 = tw[t];
  int p0 = atomicAdd(&fill[e0], 1);
  perm[p0] = t; pw[p0] = w0;
  int p1 = atomicAdd(&fill[e1], 1);
  perm[p1] = t; pw[p1] = 1.f - w0;
}

// ---------------- grouped GEMM, 128x128 tile, BK=32, 4 waves ----------------
// A: bf16 row-major, lda = K.  GATHER: row index via perm (xb); else hb rows o0+r.
// Bt: [E][Ndim][K] bf16 (pre-transposed weight).
// RELU2: out = bf16(relu(acc)^2) -> hb rows (o0+r)*Ndim.  else: atomicAdd(out[tok*Ndim+c], pw*acc)
template<bool GATHER, bool RELU2>
__global__ __launch_bounds__(256, 2)
void moe_gemm(const uint16_t* __restrict__ A, const uint16_t* __restrict__ Bt,
              const int* __restrict__ offs, const int* __restrict__ perm,
              const float* __restrict__ pw, uint16_t* __restrict__ hb,
              float* __restrict__ out, int K, int Ndim) {
  int e = blockIdx.z;
  int o0 = offs[e], o1 = offs[e + 1];
  int Me = o1 - o0;
  int rb = blockIdx.x * 128;
  if (rb >= Me) return;
  int nb = blockIdx.y * 128;

  __shared__ uint16_t smA[128 * 32];
  __shared__ uint16_t smB[128 * 32];

  int tid = threadIdx.x;
  int w = tid >> 6, l = tid & 63;
  int wr = w >> 1, wc = w & 1;

  int srow = tid >> 2;            // 0..63
  int skoff = (tid & 3) * 8;      // bf16 elements

  const uint16_t* aptr[2];
#pragma unroll
  for (int j = 0; j < 2; j++) {
    int r = rb + j * 64 + srow;
    int arow;
    if (GATHER) {
      int idx = o0 + r; if (idx > 2 * N_TOK - 1) idx = 2 * N_TOK - 1;
      arow = perm[idx];
    } else {
      arow = o0 + r; if (arow > 2 * N_TOK - 1) arow = 2 * N_TOK - 1;
    }
    aptr[j] = A + (size_t)arow * K + skoff;
  }
  const uint16_t* bbase = Bt + (size_t)e * Ndim * K;
  const uint16_t* bptr[2];
#pragma unroll
  for (int j = 0; j < 2; j++)
    bptr[j] = bbase + (size_t)(nb + j * 64 + srow) * K + skoff;

  f32x4 acc[4][4];
#pragma unroll
  for (int m = 0; m < 4; m++)
#pragma unroll
    for (int n = 0; n < 4; n++)
      acc[m][n] = (f32x4)0.f;

  for (int k0 = 0; k0 < K; k0 += 32) {
#pragma unroll
    for (int j = 0; j < 2; j++) {
      gload_lds16(aptr[j] + k0, (char*)smA + j * 4096 + w * 1024);
      gload_lds16(bptr[j] + k0, (char*)smB + j * 4096 + w * 1024);
    }
    __syncthreads();
    bf16x8 af[4], bfr[4];
#pragma unroll
    for (int m = 0; m < 4; m++)
      af[m] = *(const bf16x8*)&smA[(wr * 64 + m * 16 + (l & 15)) * 32 + (l >> 4) * 8];
#pragma unroll
    for (int n = 0; n < 4; n++)
      bfr[n] = *(const bf16x8*)&smB[(wc * 64 + n * 16 + (l & 15)) * 32 + (l >> 4) * 8];
#pragma unroll
    for (int m = 0; m < 4; m++)
#pragma unroll
      for (int n = 0; n < 4; n++)
        acc[m][n] = __builtin_amdgcn_mfma_f32_16x16x32_bf16(af[m], bfr[n], acc[m][n], 0, 0, 0);
    __syncthreads();
  }

  int cl = l & 15;
  int rg = (l >> 4) * 4;
  if (RELU2) {
#pragma unroll
    for (int m = 0; m < 4; m++) {
#pragma unroll
      for (int j = 0; j < 4; j++) {
        int er = rb + wr * 64 + m * 16 + rg + j;
        if (er < Me) {
          size_t rowoff = (size_t)(o0 + er) * Ndim;
#pragma unroll
          for (int n = 0; n < 4; n++) {
            int gc = nb + wc * 64 + n * 16 + cl;
            float v = acc[m][n][j];
            v = v > 0.f ? v * v : 0.f;
            hb[rowoff + gc] = f2bf(v);
          }
        }
      }
    }
  } else {
#pragma unroll
    for (int m = 0; m < 4; m++) {
#pragma unroll
      for (int j = 0; j < 4; j++) {
        int er = rb + wr * 64 + m * 16 + rg + j;
        if (er < Me) {
          int gi = o0 + er;
          int tok = perm[gi];
          float wgt = pw[gi];
          size_t rowoff = (size_t)tok * Ndim;
#pragma unroll
          for (int n = 0; n < 4; n++) {
            int gc = nb + wc * 64 + n * 16 + cl;
            atomicAdd(&out[rowoff + gc], wgt * acc[m][n][j]);
          }
        }
      }
    }
  }
}

extern "C" void kernel_launch(void* const* d_in, const int* in_sizes, int n_in,
                              void* d_out, int out_size, void* d_ws, size_t ws_size,
                              hipStream_t stream) {
  const float* x  = (const float*)d_in[0];
  const float* Wr = (const float*)d_in[1];
  const float* W1 = (const float*)d_in[2];
  const float* W2 = (const float*)d_in[3];
  float* out = (float*)d_out;

  char* ws = (char*)d_ws;
  size_t off = 0;
  uint16_t* xb  = (uint16_t*)(ws + off); off += (size_t)N_TOK * CDIM * 2;
  uint16_t* W1t = (uint16_t*)(ws + off); off += (size_t)NEXP * CDIM * HDIM * 2;
  uint16_t* W2t = (uint16_t*)(ws + off); off += (size_t)NEXP * CDIM * HDIM * 2;
  uint16_t* hb  = (uint16_t*)(ws + off); off += (size_t)2 * N_TOK * HDIM * 2;
  int*   perm = (int*)(ws + off); off += (size_t)2 * N_TOK * 4;
  float* pwt  = (float*)(ws + off); off += (size_t)2 * N_TOK * 4;
  int*   te   = (int*)(ws + off); off += (size_t)N_TOK * 4;
  float* tw   = (float*)(ws + off); off += (size_t)N_TOK * 4;
  int*   cnt  = (int*)(ws + off); off += 16 * 4;
  int*   offs = (int*)(ws + off); off += 16 * 4;
  int*   fill = (int*)(ws + off); off += 16 * 4;

  hipMemsetAsync(d_out, 0, (size_t)out_size * sizeof(float), stream);
  hipMemsetAsync(cnt, 0, 16 * 4, stream);

  cvt_x_kernel<<<4096, 256, 0, stream>>>(x, xb);
  transcvt_kernel<<<dim3(HDIM / 32, CDIM / 32, NEXP), dim3(32, 8), 0, stream>>>(W1, W1t, CDIM, HDIM);
  transcvt_kernel<<<dim3(CDIM / 32, HDIM / 32, NEXP), dim3(32, 8), 0, stream>>>(W2, W2t, HDIM, CDIM);
  router_kernel<<<N_TOK / 4, 256, 0, stream>>>(x, Wr, cnt, te, tw);
  prefix_kernel<<<1, 64, 0, stream>>>(cnt, offs, fill);
  bucket_kernel<<<N_TOK / 256, 256, 0, stream>>>(te, tw, fill, perm, pwt);
  moe_gemm<true, true><<<dim3(64, HDIM / 128, NEXP), 256, 0, stream>>>(
      xb, W1t, offs, perm, pwt, hb, out, CDIM, HDIM);
  moe_gemm<false, false><<<dim3(64, CDIM / 128, NEXP), 256, 0, stream>>>(
      hb, W2t, offs, perm, pwt, hb, out, HDIM, CDIM);
}